// Round 8
// baseline (398.212 us; speedup 1.0000x reference)
//
#include <hip/hip_runtime.h>
#include <hip/hip_bf16.h>

#define DI __device__ __forceinline__

typedef __attribute__((ext_vector_type(8))) short short8;
typedef __attribute__((ext_vector_type(4))) float f32x4;
typedef unsigned short u16;
typedef unsigned int u32;

DI u16 f2bf(float f){
  u32 x = __builtin_bit_cast(u32, f);
  x += 0x7fffu + ((x >> 16) & 1u);
  return (u16)(x >> 16);
}

DI u32 cvtpk(float lo, float hi){
  u32 r;
  asm("v_cvt_pk_bf16_f32 %0, %1, %2" : "=v"(r) : "v"(lo), "v"(hi));
  return r;
}

DI void gload_lds16(const u16* g, u16* l){
  __builtin_amdgcn_global_load_lds((const __attribute__((address_space(1))) void*)g,
                                   (__attribute__((address_space(3))) void*)l, 16, 0, 0);
}

// ---------------- tiled transpose: src[K][N] f32 -> dst[N][K] bf16 ----------------
__global__ __launch_bounds__(256) void k_tt(const float* __restrict__ src,
                                            u16* __restrict__ dst,
                                            int src_ld, int dst_ld){
  __shared__ float T[64][65];
  const int k0 = blockIdx.x * 64, n0 = blockIdx.y * 64;
  const int tid = threadIdx.x;
  const int r4 = tid >> 4, c4 = (tid & 15) * 4;
  #pragma unroll
  for(int p = 0; p < 4; ++p){
    const int kr = p * 16 + r4;
    const float4 v = *(const float4*)(src + (long)(k0 + kr) * src_ld + n0 + c4);
    T[kr][c4] = v.x; T[kr][c4 + 1] = v.y; T[kr][c4 + 2] = v.z; T[kr][c4 + 3] = v.w;
  }
  __syncthreads();
  const int nr = tid >> 3, kc = (tid & 7) * 8;
  #pragma unroll
  for(int p = 0; p < 2; ++p){
    const int n = p * 32 + nr;
    short8 o;
    #pragma unroll
    for(int i = 0; i < 8; ++i) o[i] = (short)f2bf(T[kc + i][n]);
    *(short8*)(dst + (long)(n0 + n) * dst_ld + k0 + kc) = o;
  }
}

// qkv pack: w{q,k,v}[h][k][f] -> dst[(which*1024 + h*64 + f)][k]
__global__ __launch_bounds__(256) void k_ttq(const float* __restrict__ wq,
                                             const float* __restrict__ wk,
                                             const float* __restrict__ wv,
                                             u16* __restrict__ dst){
  __shared__ float T[64][65];
  const int k0 = blockIdx.x * 64;
  const int y = blockIdx.y, which = y >> 4, hh = y & 15;
  const float* w = (which == 0) ? wq : ((which == 1) ? wk : wv);
  const float* s = w + (long)hh * 65536;
  const int tid = threadIdx.x;
  const int r4 = tid >> 4, c4 = (tid & 15) * 4;
  #pragma unroll
  for(int p = 0; p < 4; ++p){
    const int kr = p * 16 + r4;
    const float4 v = *(const float4*)(s + (long)(k0 + kr) * 64 + c4);
    T[kr][c4] = v.x; T[kr][c4 + 1] = v.y; T[kr][c4 + 2] = v.z; T[kr][c4 + 3] = v.w;
  }
  __syncthreads();
  const int nr = tid >> 3, kc = (tid & 7) * 8;
  u16* drow = dst + (long)y * 64 * 1024;
  #pragma unroll
  for(int p = 0; p < 2; ++p){
    const int f = p * 32 + nr;
    short8 o;
    #pragma unroll
    for(int i = 0; i < 8; ++i) o[i] = (short)f2bf(T[kc + i][f]);
    *(short8*)(drow + (long)f * 1024 + k0 + kc) = o;
  }
}

// ---------------- layernorm: fp32 [rows][1024] -> bf16 ----------------
__global__ __launch_bounds__(256) void k_ln(const float* __restrict__ x,
                                            const float* __restrict__ g,
                                            const float* __restrict__ be,
                                            u16* __restrict__ out){
  const int row = blockIdx.x;
  const int t = threadIdx.x;
  const float4 v = ((const float4*)(x + (long)row * 1024))[t];
  float s = v.x + v.y + v.z + v.w;
  #pragma unroll
  for(int o = 32; o >= 1; o >>= 1) s += __shfl_xor(s, o);
  __shared__ float r1[4], r2[4];
  if((t & 63) == 0) r1[t >> 6] = s;
  __syncthreads();
  const float mean = (r1[0] + r1[1] + r1[2] + r1[3]) * (1.f / 1024.f);
  const float dx = v.x - mean, dy = v.y - mean, dz = v.z - mean, dw = v.w - mean;
  float sq = dx*dx + dy*dy + dz*dz + dw*dw;
  #pragma unroll
  for(int o = 32; o >= 1; o >>= 1) sq += __shfl_xor(sq, o);
  if((t & 63) == 0) r2[t >> 6] = sq;
  __syncthreads();
  const float var = (r2[0] + r2[1] + r2[2] + r2[3]) * (1.f / 1024.f);
  const float rs = rsqrtf(var + 1e-5f);
  const float4 gg = ((const float4*)g)[t];
  const float4 bb = ((const float4*)be)[t];
  ushort4 ov;
  ov.x = f2bf(dx * rs * gg.x + bb.x);
  ov.y = f2bf(dy * rs * gg.y + bb.y);
  ov.z = f2bf(dz * rs * gg.z + bb.z);
  ov.w = f2bf(dw * rs * gg.w + bb.w);
  *((ushort4*)(out + (long)row * 1024) + t) = ov;
}

// ============ 256x256 8-wave BK=64 GEMM, MODES 0 (qkv, q pre-scaled) & 2 (relu) ====
template<int MODE>
__global__ __launch_bounds__(512) void k_gemm256(
    const u16* __restrict__ A, const u16* __restrict__ BT,
    int M, int N, int K,
    const float* __restrict__ bias, u16* __restrict__ outh,
    u16* __restrict__ qo, u16* __restrict__ ko, u16* __restrict__ vo){
  __shared__ __align__(16) u16 lds[65536];   // 128 KiB: [2 buf][A|B][2 kh][256r][32c]
  const int tid = threadIdx.x;
  const int wid = tid >> 6, lane = tid & 63;
  const int lq = lane & 15, lg = lane >> 4;
  const int wm = wid >> 2, wn = wid & 3;
  const int rsw = (lq >> 1) & 3;

  // XCD-bijective + grouped (8m x NT) swizzle: each XCD works a panel square
  const int nwg = gridDim.x;
  const int orig = blockIdx.x;
  const int wg = (orig & 7) * (nwg >> 3) + (orig >> 3);
  const int NT = N >> 8;
  const int gsz = 8 * NT;
  const int gid = wg / gsz, rem = wg % gsz;
  const int m0 = (gid * 8 + (rem & 7)) << 8;
  const int n0 = (rem >> 3) << 8;

  const int NTILES = K >> 6;

  auto stageHalf = [&](int buf, int mat, int kh, int kt){
    const u16* __restrict__ src = mat ? BT : A;
    const int base = mat ? n0 : m0;
    const long kcol = (long)kt * 64 + kh * 32;
    u16* dstb = &lds[buf * 32768 + mat * 16384 + kh * 8192];
    #pragma unroll
    for(int c = 0; c < 2; ++c){
      int g = c * 512 + tid;
      int row = g >> 2, p = g & 3;
      int sp = p ^ ((row >> 1) & 3);
      gload_lds16(src + (long)(base + row) * K + kcol + sp * 8, dstb + g * 8);
    }
  };
  auto LDA_ = [&](int buf, int kk, int m)->short8{
    return *(const short8*)&lds[buf * 32768 + kk * 8192 +
                                (wm * 128 + m * 16 + lq) * 32 + ((lg ^ rsw) * 8)];
  };
  auto LDB_ = [&](int buf, int kk, int n)->short8{
    return *(const short8*)&lds[buf * 32768 + 16384 + kk * 8192 +
                                (wn * 64 + n * 16 + lq) * 32 + ((lg ^ rsw) * 8)];
  };

  f32x4 acc[8][4] = {};
  short8 af[8], bfr[4];

  stageHalf(0, 0, 0, 0); stageHalf(0, 1, 0, 0);
  stageHalf(0, 0, 1, 0); stageHalf(0, 1, 1, 0);
  asm volatile("s_waitcnt vmcnt(4)" ::: "memory");
  __builtin_amdgcn_s_barrier();

  for(int kt = 0; kt < NTILES; ++kt){
    const int cb = kt & 1, nb = cb ^ 1;
    const bool pf = (kt + 1 < NTILES);
    // ---- phase 1: k0, m0..3 ----
    #pragma unroll
    for(int m = 0; m < 4; ++m) af[m] = LDA_(cb, 0, m);
    #pragma unroll
    for(int n = 0; n < 4; ++n) bfr[n] = LDB_(cb, 0, n);
    if(pf) stageHalf(nb, 0, 0, kt + 1);
    __builtin_amdgcn_s_barrier();
    asm volatile("s_waitcnt lgkmcnt(0)" ::: "memory");
    __builtin_amdgcn_sched_barrier(0);
    __builtin_amdgcn_s_setprio(1);
    #pragma unroll
    for(int m = 0; m < 4; ++m)
      #pragma unroll
      for(int n = 0; n < 4; ++n)
        acc[m][n] = __builtin_amdgcn_mfma_f32_16x16x32_bf16(af[m], bfr[n], acc[m][n], 0, 0, 0);
    __builtin_amdgcn_s_setprio(0);
    __builtin_amdgcn_sched_barrier(0);
    __builtin_amdgcn_s_barrier();
    // ---- phase 2: k0, m4..7 ----
    #pragma unroll
    for(int m = 0; m < 4; ++m) af[4 + m] = LDA_(cb, 0, 4 + m);
    if(pf) stageHalf(nb, 1, 0, kt + 1);
    __builtin_amdgcn_s_barrier();
    asm volatile("s_waitcnt lgkmcnt(0)" ::: "memory");
    __builtin_amdgcn_sched_barrier(0);
    __builtin_amdgcn_s_setprio(1);
    #pragma unroll
    for(int m = 0; m < 4; ++m)
      #pragma unroll
      for(int n = 0; n < 4; ++n)
        acc[4 + m][n] = __builtin_amdgcn_mfma_f32_16x16x32_bf16(af[4 + m], bfr[n], acc[4 + m][n], 0, 0, 0);
    __builtin_amdgcn_s_setprio(0);
    if(pf) asm volatile("s_waitcnt vmcnt(4)" ::: "memory");
    else   asm volatile("s_waitcnt vmcnt(0)" ::: "memory");
    __builtin_amdgcn_sched_barrier(0);
    __builtin_amdgcn_s_barrier();
    // ---- phase 3: k1, m0..3 ----
    #pragma unroll
    for(int m = 0; m < 4; ++m) af[m] = LDA_(cb, 1, m);
    #pragma unroll
    for(int n = 0; n < 4; ++n) bfr[n] = LDB_(cb, 1, n);
    if(pf) stageHalf(nb, 0, 1, kt + 1);
    __builtin_amdgcn_s_barrier();
    asm volatile("s_waitcnt lgkmcnt(0)" ::: "memory");
    __builtin_amdgcn_sched_barrier(0);
    __builtin_amdgcn_s_setprio(1);
    #pragma unroll
    for(int m = 0; m < 4; ++m)
      #pragma unroll
      for(int n = 0; n < 4; ++n)
        acc[m][n] = __builtin_amdgcn_mfma_f32_16x16x32_bf16(af[m], bfr[n], acc[m][n], 0, 0, 0);
    __builtin_amdgcn_s_setprio(0);
    __builtin_amdgcn_sched_barrier(0);
    __builtin_amdgcn_s_barrier();
    // ---- phase 4: k1, m4..7 ----
    #pragma unroll
    for(int m = 0; m < 4; ++m) af[4 + m] = LDA_(cb, 1, 4 + m);
    if(pf) stageHalf(nb, 1, 1, kt + 1);
    __builtin_amdgcn_s_barrier();
    asm volatile("s_waitcnt lgkmcnt(0)" ::: "memory");
    __builtin_amdgcn_sched_barrier(0);
    __builtin_amdgcn_s_setprio(1);
    #pragma unroll
    for(int m = 0; m < 4; ++m)
      #pragma unroll
      for(int n = 0; n < 4; ++n)
        acc[4 + m][n] = __builtin_amdgcn_mfma_f32_16x16x32_bf16(af[4 + m], bfr[n], acc[4 + m][n], 0, 0, 0);
    __builtin_amdgcn_s_setprio(0);
    if(pf) asm volatile("s_waitcnt vmcnt(4)" ::: "memory");
    __builtin_amdgcn_sched_barrier(0);
    __builtin_amdgcn_s_barrier();
  }

  constexpr float CE = 0.03125f * 1.44269504088896f;  // attn scale * log2(e), folded into q
  #pragma unroll
  for(int m = 0; m < 8; ++m){
    #pragma unroll
    for(int n = 0; n < 4; ++n){
      #pragma unroll
      for(int r = 0; r < 4; ++r){
        const int row = m0 + wm * 128 + m * 16 + lg * 4 + r;
        const int col = n0 + wn * 64 + n * 16 + lq;
        float val = acc[m][n][r];
        if constexpr(MODE == 0){
          int which = col >> 10, hh = (col >> 6) & 15, f = col & 63;
          int b = row >> 11, t = row & 2047;
          if(which == 0) val *= CE;
          u16* dst = (which == 0) ? qo : ((which == 1) ? ko : vo);
          dst[((((long)(b * 16 + hh)) << 11 | t) << 6) | f] = f2bf(val);
        } else {
          const float z = val + bias[col];
          outh[(long)row * N + col] = f2bf(z > 0.f ? z : 0.f);
        }
      }
    }
  }
}

// ======== 256x128 8-wave BK=64 GEMM, 2 phases/tile: C = A*BT^T + bias + resid ======
__global__ __launch_bounds__(512) void k_gemmN128(
    const u16* __restrict__ A, const u16* __restrict__ BT,
    int M, int N, int K,
    const float* __restrict__ bias, const float* __restrict__ resid,
    float* __restrict__ outf){
  __shared__ __align__(16) u16 lds[49152];   // 96 KiB: [2][A 2kh 256x32 | B 2kh 128x32]
  const int tid = threadIdx.x;
  const int wid = tid >> 6, lane = tid & 63;
  const int lq = lane & 15, lg = lane >> 4;
  const int wm = wid >> 1, wn = wid & 1;
  const int rsw = (lq >> 1) & 3;

  const int nwg = gridDim.x;
  const int orig = blockIdx.x;
  const int wg = (orig & 7) * (nwg >> 3) + (orig >> 3);
  const int NT = N >> 7;
  const int gsz = 8 * NT;
  const int gid = wg / gsz, rem = wg % gsz;
  const int m0 = (gid * 8 + (rem & 7)) << 8;
  const int n0 = (rem >> 3) << 7;

  const int NTILES = K >> 6;

  auto stageA = [&](int buf, int kh, int kt){
    const long kcol = (long)kt * 64 + kh * 32;
    u16* dstb = &lds[buf * 24576 + kh * 8192];
    #pragma unroll
    for(int c = 0; c < 2; ++c){
      int g = c * 512 + tid;
      int row = g >> 2, p = g & 3;
      int sp = p ^ ((row >> 1) & 3);
      gload_lds16(A + (long)(m0 + row) * K + kcol + sp * 8, dstb + g * 8);
    }
  };
  auto stageB = [&](int buf, int kh, int kt){
    const long kcol = (long)kt * 64 + kh * 32;
    u16* dstb = &lds[buf * 24576 + 16384 + kh * 4096];
    int row = tid >> 2, p = tid & 3;
    int sp = p ^ ((row >> 1) & 3);
    gload_lds16(BT + (long)(n0 + row) * K + kcol + sp * 8, dstb + tid * 8);
  };
  auto LDA_ = [&](int buf, int kk, int m)->short8{
    return *(const short8*)&lds[buf * 24576 + kk * 8192 +
                                (wm * 64 + m * 16 + lq) * 32 + ((lg ^ rsw) * 8)];
  };
  auto LDB_ = [&](int buf, int kk, int n)->short8{
    return *(const short8*)&lds[buf * 24576 + 16384 + kk * 4096 +
                                (wn * 64 + n * 16 + lq) * 32 + ((lg ^ rsw) * 8)];
  };

  f32x4 acc[4][4] = {};
  short8 af[4], bfr[4];

  stageA(0, 0, 0); stageB(0, 0, 0); stageA(0, 1, 0); stageB(0, 1, 0);
  asm volatile("s_waitcnt vmcnt(3)" ::: "memory");
  __builtin_amdgcn_s_barrier();

  for(int kt = 0; kt < NTILES; ++kt){
    const int cb = kt & 1, nb = cb ^ 1;
    const bool pf = (kt + 1 < NTILES);
    // ---- phase 1: kk0 ----
    #pragma unroll
    for(int m = 0; m < 4; ++m) af[m] = LDA_(cb, 0, m);
    #pragma unroll
    for(int n = 0; n < 4; ++n) bfr[n] = LDB_(cb, 0, n);
    if(pf){ stageA(nb, 0, kt + 1); stageB(nb, 0, kt + 1); }
    __builtin_amdgcn_s_barrier();
    asm volatile("s_waitcnt lgkmcnt(0)" ::: "memory");
    __builtin_amdgcn_sched_barrier(0);
    __builtin_amdgcn_s_setprio(1);
    #pragma unroll
    for(int m = 0; m < 4; ++m)
      #pragma unroll
      for(int n = 0; n < 4; ++n)
        acc[m][n] = __builtin_amdgcn_mfma_f32_16x16x32_bf16(af[m], bfr[n], acc[m][n], 0, 0, 0);
    __builtin_amdgcn_s_setprio(0);
    if(pf) asm volatile("s_waitcnt vmcnt(3)" ::: "memory");
    else   asm volatile("s_waitcnt vmcnt(0)" ::: "memory");
    __builtin_amdgcn_sched_barrier(0);
    __builtin_amdgcn_s_barrier();
    // ---- phase 2: kk1 ----
    #pragma unroll
    for(int m = 0; m < 4; ++m) af[m] = LDA_(cb, 1, m);
    #pragma unroll
    for(int n = 0; n < 4; ++n) bfr[n] = LDB_(cb, 1, n);
    if(pf){ stageA(nb, 1, kt + 1); stageB(nb, 1, kt + 1); }
    __builtin_amdgcn_s_barrier();
    asm volatile("s_waitcnt lgkmcnt(0)" ::: "memory");
    __builtin_amdgcn_sched_barrier(0);
    __builtin_amdgcn_s_setprio(1);
    #pragma unroll
    for(int m = 0; m < 4; ++m)
      #pragma unroll
      for(int n = 0; n < 4; ++n)
        acc[m][n] = __builtin_amdgcn_mfma_f32_16x16x32_bf16(af[m], bfr[n], acc[m][n], 0, 0, 0);
    __builtin_amdgcn_s_setprio(0);
    if(pf){
      asm volatile("s_waitcnt vmcnt(3)" ::: "memory");
      __builtin_amdgcn_sched_barrier(0);
      __builtin_amdgcn_s_barrier();
    }
  }

  #pragma unroll
  for(int m = 0; m < 4; ++m)
    #pragma unroll
    for(int n = 0; n < 4; ++n)
      #pragma unroll
      for(int r = 0; r < 4; ++r){
        const int row = m0 + wm * 64 + m * 16 + lg * 4 + r;
        const int col = n0 + wn * 64 + n * 16 + lq;
        const long o = (long)row * N + col;
        outf[o] = acc[m][n][r] + bias[col] + resid[o];
      }
}

// ---------------- V transpose: [bh][t][f] -> [bh][f][t] ----------------
__global__ __launch_bounds__(256) void k_vtrans(const u16* __restrict__ vb,
                                                u16* __restrict__ vt){
  __shared__ u16 T[64][72];
  const int tid = threadIdx.x;
  const int tt = blockIdx.x, bh = blockIdx.y;
  const long base_in = ((long)bh << 17) + ((long)tt << 12);
  #pragma unroll
  for(int c = 0; c < 2; ++c){
    int idx = (c * 256 + tid) * 8;
    int t = idx >> 6, f = idx & 63;
    short8 v = *(const short8*)(vb + base_in + idx);
    #pragma unroll
    for(int i = 0; i < 8; ++i) T[f + i][t] = (u16)v[i];
  }
  __syncthreads();
  const long base_out = ((long)bh << 17) + tt * 64;
  #pragma unroll
  for(int c = 0; c < 2; ++c){
    int idx = (c * 256 + tid) * 8;
    int f = idx >> 6, t0 = idx & 63;
    short8 o = *(const short8*)&T[f][t0];
    *(short8*)(vt + base_out + (long)f * 2048 + t0) = o;
  }
}

// -------- flash attention v6: paired causal q-tiles; amdgpu_waves_per_eu(4,4)
//          pins the register budget to 128 VGPRs (4 waves/SIMD = the LDS cap) so the
//          paired accumulators live in registers, not scratch. -----------------------
__global__ __launch_bounds__(256) __attribute__((amdgpu_waves_per_eu(4, 4)))
void k_attn(const u16* __restrict__ q,
            const u16* __restrict__ k,
            const u16* __restrict__ vt,
            u16* __restrict__ att){
  __shared__ __align__(16) u16 Ks[2][2][64][32];
  __shared__ __align__(16) u16 Vs[2][2][64][32];
  __shared__ __align__(16) u16 Ps[4][16][64];
  const int tid = threadIdx.x, wid = tid >> 6, lane = tid & 63;
  const int lq = lane & 15, lg = lane >> 4;
  const int d = blockIdx.x;
  const int bh = (d & 7) * 8 + ((d >> 3) & 7);
  const int i = d >> 6;
  const int qa = i, qb = 31 - i;
  const int b = bh >> 4, h = bh & 15;
  const long bhO = (long)bh << 17;
  const u16* Kg = k + bhO;
  const u16* Vg = vt + bhO;

  short8 qfa[2], qfb[2];
  {
    const u16* ra = q + bhO + ((long)qa << 12) + (wid * 16 + lq) * 64 + lg * 8;
    qfa[0] = *(const short8*)(ra);
    qfa[1] = *(const short8*)(ra + 32);
    const u16* rb = q + bhO + ((long)qb << 12) + (wid * 16 + lq) * 64 + lg * 8;
    qfb[0] = *(const short8*)(rb);
    qfb[1] = *(const short8*)(rb + 32);
  }

  auto stageKV = [&](int buf, int kv){
    #pragma unroll
    for(int c = 0; c < 2; ++c){
      int s = (c * 256 + tid) * 8;
      int kk = s >> 11, row = (s >> 5) & 63, t = (s >> 3) & 3;
      int sw = (t ^ ((row >> 1) & 3)) * 8;
      gload_lds16(Kg + (long)kv * 4096 + row * 64 + kk * 32 + sw, &Ks[buf][0][0][0] + s);
      gload_lds16(Vg + (long)row * 2048 + kv * 64 + kk * 32 + sw, &Vs[buf][0][0][0] + s);
    }
  };
  stageKV(0, 0);

  float la = 0.f, lb = 0.f;
  f32x4 Oa[4] = {}, Ob[4] = {};
  const int qga = qa * 64 + wid * 16 + lq;
  const int qgb = qb * 64 + wid * 16 + lq;
  const int swz = (lq >> 1) & 3;
  const int psw = lq & 7;

// All-macro tile step: every array index compile-time -> accumulators stay in VGPRs.
#define DOTILE(QF, OF, LRUN, QG, DIAG, KVB, CB)                                      \
  do{                                                                                \
    f32x4 sf0 = {}, sf1 = {}, sf2 = {}, sf3 = {};                                    \
    _Pragma("unroll")                                                                \
    for(int kk = 0; kk < 2; ++kk){                                                   \
      short8 a0 = *(const short8*)&Ks[CB][kk][ 0 + lq][(lg ^ swz) * 8];              \
      short8 a1 = *(const short8*)&Ks[CB][kk][16 + lq][(lg ^ swz) * 8];              \
      short8 a2 = *(const short8*)&Ks[CB][kk][32 + lq][(lg ^ swz) * 8];              \
      short8 a3 = *(const short8*)&Ks[CB][kk][48 + lq][(lg ^ swz) * 8];              \
      sf0 = __builtin_amdgcn_mfma_f32_16x16x32_bf16(a0, QF[kk], sf0, 0, 0, 0);       \
      sf1 = __builtin_amdgcn_mfma_f32_16x16x32_bf16(a1, QF[kk], sf1, 0, 0, 0);       \
      sf2 = __builtin_amdgcn_mfma_f32_16x16x32_bf16(a2, QF[kk], sf2, 0, 0, 0);       \
      sf3 = __builtin_amdgcn_mfma_f32_16x16x32_bf16(a3, QF[kk], sf3, 0, 0, 0);       \
    }                                                                                \
    float se = 0.f;                                                                  \
    _Pragma("unroll")                                                                \
    for(int r = 0; r < 4; ++r){                                                      \
      float p0 = __builtin_amdgcn_exp2f(sf0[r]);                                     \
      float p1 = __builtin_amdgcn_exp2f(sf1[r]);                                     \
      float p2 = __builtin_amdgcn_exp2f(sf2[r]);                                     \
      float p3 = __builtin_amdgcn_exp2f(sf3[r]);                                     \
      if(DIAG){                                                                      \
        const int kg = (KVB) + lg * 4 + r;                                           \
        p0 = (kg      > (QG)) ? 0.f : p0;                                            \
        p1 = (kg + 16 > (QG)) ? 0.f : p1;                                            \
        p2 = (kg + 32 > (QG)) ? 0.f : p2;                                            \
        p3 = (kg + 48 > (QG)) ? 0.f : p3;                                            \
      }                                                                              \
      sf0[r] = p0; sf1[r] = p1; sf2[r] = p2; sf3[r] = p3;                            \
      se += (p0 + p1) + (p2 + p3);                                                   \
    }                                                                                \
    {                                                                                \
      uint2 w0, w1, w2, w3;                                                          \
      w0.x = cvtpk(sf0[0], sf0[1]); w0.y = cvtpk(sf0[2], sf0[3]);                    \
      w1.x = cvtpk(sf1[0], sf1[1]); w1.y = cvtpk(sf1[2], sf1[3]);                    \
      w2.x = cvtpk(sf2[0], sf2[1]); w2.y = cvtpk(sf2[2], sf2[3]);                    \
      w3.x = cvtpk(sf3[0], sf3[1]); w3.y = cvtpk(sf3[2], sf3[3]);                    \
      *(uint2*)&Ps[wid][lq][((0 + (lg >> 1)) ^ psw) * 8 + (lg & 1) * 4] = w0;        \
      *(uint2*)&Ps[wid][lq][((2 + (lg >> 1)) ^ psw) * 8 + (lg & 1) * 4] = w1;        \
      *(uint2*)&Ps[wid][lq][((4 + (lg >> 1)) ^ psw) * 8 + (lg & 1) * 4] = w2;        \
      *(uint2*)&Ps[wid][lq][((6 + (lg >> 1)) ^ psw) * 8 + (lg & 1) * 4] = w3;        \
    }                                                                                \
    se += __shfl_xor(se, 16);                                                        \
    se += __shfl_xor(se, 32);                                                        \
    LRUN += se;                                                                      \
    _Pragma("unroll")                                                                \
    for(int kk = 0; kk < 2; ++kk){                                                   \
      short8 ap = *(const short8*)&Ps[wid][lq][((kk * 4 + lg) ^ psw) * 8];           \
      short8 b0 = *(const short8*)&Vs[CB][kk][ 0 + lq][(lg ^ swz) * 8];              \
      short8 b1 = *(const short8*)&Vs[CB][kk][16 + lq][(lg ^ swz) * 8];              \
      short8 b2 = *(const short8*)&Vs[CB][kk][32 + lq][(lg ^ swz) * 8];              \
      short8 b3 = *(const short8*)&Vs[CB][kk][48 + lq][(lg ^ swz) * 8];              \
      OF[0] = __builtin_amdgcn_mfma_f32_16x16x32_bf16(ap, b0, OF[0], 0, 0, 0);       \
      OF[1] = __builtin_amdgcn_mfma_f32_16x16x32_bf16(ap, b1, OF[1], 0, 0, 0);       \
      OF[2] = __builtin_amdgcn_mfma_f32_16x16x32_bf16(ap, b2, OF[2], 0, 0, 0);       \
      OF[3] = __builtin_amdgcn_mfma_f32_16x16x32_bf16(ap, b3, OF[3], 0, 0, 0);       \
    }                                                                                \
  } while(0)

  for(int kv = 0; kv <= qb; ++kv){
    __syncthreads();
    const int cb = kv & 1;
    if(kv < qb) stageKV(cb ^ 1, kv + 1);
    DOTILE(qfb, Ob, lb, qgb, (kv == qb), kv * 64, cb);
    if(kv <= qa) DOTILE(qfa, Oa, la, qga, (kv == qa), kv * 64, cb);
  }

#define WRITEO(OF, LRUN, QT)                                                         \
  do{                                                                                \
    const float rl = 1.f / (LRUN);                                                   \
    _Pragma("unroll")                                                                \
    for(int r = 0; r < 4; ++r){                                                      \
      const float il = __shfl(rl, lg * 4 + r);                                       \
      const long grow = (long)b * 2048 + (QT) * 64 + wid * 16 + lg * 4 + r;          \
      att[grow * 1024 + h * 64 +  0 + lq] = f2bf(OF[0][r] * il);                     \
      att[grow * 1024 + h * 64 + 16 + lq] = f2bf(OF[1][r] * il);                     \
      att[grow * 1024 + h * 64 + 32 + lq] = f2bf(OF[2][r] * il);                     \
      att[grow * 1024 + h * 64 + 48 + lq] = f2bf(OF[3][r] * il);                     \
    }                                                                                \
  } while(0)

  WRITEO(Oa, la, qa);
  WRITEO(Ob, lb, qb);
#undef DOTILE
#undef WRITEO
}

extern "C" void kernel_launch(void* const* d_in, const int* in_sizes, int n_in,
                              void* d_out, int out_size, void* d_ws, size_t ws_size,
                              hipStream_t stream){
  const float* x      = (const float*)d_in[0];
  const float* wq     = (const float*)d_in[1];
  const float* wk     = (const float*)d_in[2];
  const float* wv     = (const float*)d_in[3];
  const float* w_proj = (const float*)d_in[4];
  const float* b_proj = (const float*)d_in[5];
  const float* g1     = (const float*)d_in[6];
  const float* beta1  = (const float*)d_in[7];
  const float* g2     = (const float*)d_in[8];
  const float* beta2  = (const float*)d_in[9];
  const float* w1     = (const float*)d_in[10];
  const float* bf1    = (const float*)d_in[11];
  const float* w2     = (const float*)d_in[12];
  const float* bf2    = (const float*)d_in[13];
  float* out = (float*)d_out;

  u16* WqkvT  = (u16*)d_ws;
  u16* wprojT = WqkvT  + (long)3072 * 1024;
  u16* w1T    = wprojT + (long)1024 * 1024;
  u16* w2T    = w1T    + (long)4096 * 1024;
  u16* h1     = w2T    + (long)4096 * 1024;   // reused for h2
  u16* qb     = h1     + (long)8192 * 1024;
  u16* kb     = qb     + (long)8388608;
  u16* vb     = kb     + (long)8388608;
  u16* tb     = vb     + (long)8388608;       // V^T; att output reuses vb
  u16* a1     = qb;                            // FF1 activation reuses q/k/v/t span
  float* x2   = (float*)(tb + (long)8388608);

  k_ttq<<<dim3(16, 48), 256, 0, stream>>>(wq, wk, wv, WqkvT);
  k_tt<<<dim3(16, 16), 256, 0, stream>>>(w_proj, wprojT, 1024, 1024);
  k_tt<<<dim3(16, 64), 256, 0, stream>>>(w1, w1T, 4096, 1024);
  k_tt<<<dim3(64, 16), 256, 0, stream>>>(w2, w2T, 1024, 4096);

  k_ln<<<8192, 256, 0, stream>>>(x, g1, beta1, h1);
  k_gemm256<0><<<384, 512, 0, stream>>>(h1, WqkvT, 8192, 3072, 1024,
      nullptr, nullptr, qb, kb, vb);
  k_vtrans<<<dim3(32, 64), 256, 0, stream>>>(vb, tb);
  k_attn<<<1024, 256, 0, stream>>>(qb, kb, tb, vb);
  k_gemmN128<<<256, 512, 0, stream>>>(vb, wprojT, 8192, 1024, 1024,
      b_proj, x, x2);
  k_ln<<<8192, 256, 0, stream>>>(x2, g2, beta2, h1);
  k_gemm256<2><<<512, 512, 0, stream>>>(h1, w1T, 8192, 4096, 1024,
      bf1, a1, nullptr, nullptr, nullptr);
  k_gemmN128<<<256, 512, 0, stream>>>(a1, w2T, 8192, 1024, 4096,
      bf2, x2, out);
}

// Round 9
// 359.519 us; speedup vs baseline: 1.1076x; 1.1076x over previous
//
#include <hip/hip_runtime.h>
#include <hip/hip_bf16.h>

#define DI __device__ __forceinline__

typedef __attribute__((ext_vector_type(8))) short short8;
typedef __attribute__((ext_vector_type(4))) float f32x4;
typedef unsigned short u16;
typedef unsigned int u32;

DI u16 f2bf(float f){
  u32 x = __builtin_bit_cast(u32, f);
  x += 0x7fffu + ((x >> 16) & 1u);
  return (u16)(x >> 16);
}

DI u32 cvtpk(float lo, float hi){
  u32 r;
  asm("v_cvt_pk_bf16_f32 %0, %1, %2" : "=v"(r) : "v"(lo), "v"(hi));
  return r;
}

DI void gload_lds16(const u16* g, u16* l){
  __builtin_amdgcn_global_load_lds((const __attribute__((address_space(1))) void*)g,
                                   (__attribute__((address_space(3))) void*)l, 16, 0, 0);
}

// ---------------- tiled transpose: src[K][N] f32 -> dst[N][K] bf16 ----------------
__global__ __launch_bounds__(256) void k_tt(const float* __restrict__ src,
                                            u16* __restrict__ dst,
                                            int src_ld, int dst_ld){
  __shared__ float T[64][65];
  const int k0 = blockIdx.x * 64, n0 = blockIdx.y * 64;
  const int tid = threadIdx.x;
  const int r4 = tid >> 4, c4 = (tid & 15) * 4;
  #pragma unroll
  for(int p = 0; p < 4; ++p){
    const int kr = p * 16 + r4;
    const float4 v = *(const float4*)(src + (long)(k0 + kr) * src_ld + n0 + c4);
    T[kr][c4] = v.x; T[kr][c4 + 1] = v.y; T[kr][c4 + 2] = v.z; T[kr][c4 + 3] = v.w;
  }
  __syncthreads();
  const int nr = tid >> 3, kc = (tid & 7) * 8;
  #pragma unroll
  for(int p = 0; p < 2; ++p){
    const int n = p * 32 + nr;
    short8 o;
    #pragma unroll
    for(int i = 0; i < 8; ++i) o[i] = (short)f2bf(T[kc + i][n]);
    *(short8*)(dst + (long)(n0 + n) * dst_ld + k0 + kc) = o;
  }
}

// qkv pack: w{q,k,v}[h][k][f] -> dst[(which*1024 + h*64 + f)][k]
__global__ __launch_bounds__(256) void k_ttq(const float* __restrict__ wq,
                                             const float* __restrict__ wk,
                                             const float* __restrict__ wv,
                                             u16* __restrict__ dst){
  __shared__ float T[64][65];
  const int k0 = blockIdx.x * 64;
  const int y = blockIdx.y, which = y >> 4, hh = y & 15;
  const float* w = (which == 0) ? wq : ((which == 1) ? wk : wv);
  const float* s = w + (long)hh * 65536;
  const int tid = threadIdx.x;
  const int r4 = tid >> 4, c4 = (tid & 15) * 4;
  #pragma unroll
  for(int p = 0; p < 4; ++p){
    const int kr = p * 16 + r4;
    const float4 v = *(const float4*)(s + (long)(k0 + kr) * 64 + c4);
    T[kr][c4] = v.x; T[kr][c4 + 1] = v.y; T[kr][c4 + 2] = v.z; T[kr][c4 + 3] = v.w;
  }
  __syncthreads();
  const int nr = tid >> 3, kc = (tid & 7) * 8;
  u16* drow = dst + (long)y * 64 * 1024;
  #pragma unroll
  for(int p = 0; p < 2; ++p){
    const int f = p * 32 + nr;
    short8 o;
    #pragma unroll
    for(int i = 0; i < 8; ++i) o[i] = (short)f2bf(T[kc + i][f]);
    *(short8*)(drow + (long)f * 1024 + k0 + kc) = o;
  }
}

// ---------------- layernorm: fp32 [rows][1024] -> bf16 ----------------
__global__ __launch_bounds__(256) void k_ln(const float* __restrict__ x,
                                            const float* __restrict__ g,
                                            const float* __restrict__ be,
                                            u16* __restrict__ out){
  const int row = blockIdx.x;
  const int t = threadIdx.x;
  const float4 v = ((const float4*)(x + (long)row * 1024))[t];
  float s = v.x + v.y + v.z + v.w;
  #pragma unroll
  for(int o = 32; o >= 1; o >>= 1) s += __shfl_xor(s, o);
  __shared__ float r1[4], r2[4];
  if((t & 63) == 0) r1[t >> 6] = s;
  __syncthreads();
  const float mean = (r1[0] + r1[1] + r1[2] + r1[3]) * (1.f / 1024.f);
  const float dx = v.x - mean, dy = v.y - mean, dz = v.z - mean, dw = v.w - mean;
  float sq = dx*dx + dy*dy + dz*dz + dw*dw;
  #pragma unroll
  for(int o = 32; o >= 1; o >>= 1) sq += __shfl_xor(sq, o);
  if((t & 63) == 0) r2[t >> 6] = sq;
  __syncthreads();
  const float var = (r2[0] + r2[1] + r2[2] + r2[3]) * (1.f / 1024.f);
  const float rs = rsqrtf(var + 1e-5f);
  const float4 gg = ((const float4*)g)[t];
  const float4 bb = ((const float4*)be)[t];
  ushort4 ov;
  ov.x = f2bf(dx * rs * gg.x + bb.x);
  ov.y = f2bf(dy * rs * gg.y + bb.y);
  ov.z = f2bf(dz * rs * gg.z + bb.z);
  ov.w = f2bf(dw * rs * gg.w + bb.w);
  *((ushort4*)(out + (long)row * 1024) + t) = ov;
}

// ============ 256x256 8-wave BK=64 GEMM, MODES 0 (qkv, q pre-scaled) & 2 (relu) ====
template<int MODE>
__global__ __launch_bounds__(512) void k_gemm256(
    const u16* __restrict__ A, const u16* __restrict__ BT,
    int M, int N, int K,
    const float* __restrict__ bias, u16* __restrict__ outh,
    u16* __restrict__ qo, u16* __restrict__ ko, u16* __restrict__ vo){
  __shared__ __align__(16) u16 lds[65536];   // 128 KiB: [2 buf][A|B][2 kh][256r][32c]
  const int tid = threadIdx.x;
  const int wid = tid >> 6, lane = tid & 63;
  const int lq = lane & 15, lg = lane >> 4;
  const int wm = wid >> 2, wn = wid & 3;
  const int rsw = (lq >> 1) & 3;

  // XCD-bijective + grouped (8m x NT) swizzle: each XCD works a panel square
  const int nwg = gridDim.x;
  const int orig = blockIdx.x;
  const int wg = (orig & 7) * (nwg >> 3) + (orig >> 3);
  const int NT = N >> 8;
  const int gsz = 8 * NT;
  const int gid = wg / gsz, rem = wg % gsz;
  const int m0 = (gid * 8 + (rem & 7)) << 8;
  const int n0 = (rem >> 3) << 8;

  const int NTILES = K >> 6;

  auto stageHalf = [&](int buf, int mat, int kh, int kt){
    const u16* __restrict__ src = mat ? BT : A;
    const int base = mat ? n0 : m0;
    const long kcol = (long)kt * 64 + kh * 32;
    u16* dstb = &lds[buf * 32768 + mat * 16384 + kh * 8192];
    #pragma unroll
    for(int c = 0; c < 2; ++c){
      int g = c * 512 + tid;
      int row = g >> 2, p = g & 3;
      int sp = p ^ ((row >> 1) & 3);
      gload_lds16(src + (long)(base + row) * K + kcol + sp * 8, dstb + g * 8);
    }
  };
  auto LDA_ = [&](int buf, int kk, int m)->short8{
    return *(const short8*)&lds[buf * 32768 + kk * 8192 +
                                (wm * 128 + m * 16 + lq) * 32 + ((lg ^ rsw) * 8)];
  };
  auto LDB_ = [&](int buf, int kk, int n)->short8{
    return *(const short8*)&lds[buf * 32768 + 16384 + kk * 8192 +
                                (wn * 64 + n * 16 + lq) * 32 + ((lg ^ rsw) * 8)];
  };

  f32x4 acc[8][4] = {};
  short8 af[8], bfr[4];

  stageHalf(0, 0, 0, 0); stageHalf(0, 1, 0, 0);
  stageHalf(0, 0, 1, 0); stageHalf(0, 1, 1, 0);
  asm volatile("s_waitcnt vmcnt(4)" ::: "memory");
  __builtin_amdgcn_s_barrier();

  for(int kt = 0; kt < NTILES; ++kt){
    const int cb = kt & 1, nb = cb ^ 1;
    const bool pf = (kt + 1 < NTILES);
    // ---- phase 1: k0, m0..3 ----
    #pragma unroll
    for(int m = 0; m < 4; ++m) af[m] = LDA_(cb, 0, m);
    #pragma unroll
    for(int n = 0; n < 4; ++n) bfr[n] = LDB_(cb, 0, n);
    if(pf) stageHalf(nb, 0, 0, kt + 1);
    __builtin_amdgcn_s_barrier();
    asm volatile("s_waitcnt lgkmcnt(0)" ::: "memory");
    __builtin_amdgcn_sched_barrier(0);
    __builtin_amdgcn_s_setprio(1);
    #pragma unroll
    for(int m = 0; m < 4; ++m)
      #pragma unroll
      for(int n = 0; n < 4; ++n)
        acc[m][n] = __builtin_amdgcn_mfma_f32_16x16x32_bf16(af[m], bfr[n], acc[m][n], 0, 0, 0);
    __builtin_amdgcn_s_setprio(0);
    __builtin_amdgcn_sched_barrier(0);
    __builtin_amdgcn_s_barrier();
    // ---- phase 2: k0, m4..7 ----
    #pragma unroll
    for(int m = 0; m < 4; ++m) af[4 + m] = LDA_(cb, 0, 4 + m);
    if(pf) stageHalf(nb, 1, 0, kt + 1);
    __builtin_amdgcn_s_barrier();
    asm volatile("s_waitcnt lgkmcnt(0)" ::: "memory");
    __builtin_amdgcn_sched_barrier(0);
    __builtin_amdgcn_s_setprio(1);
    #pragma unroll
    for(int m = 0; m < 4; ++m)
      #pragma unroll
      for(int n = 0; n < 4; ++n)
        acc[4 + m][n] = __builtin_amdgcn_mfma_f32_16x16x32_bf16(af[4 + m], bfr[n], acc[4 + m][n], 0, 0, 0);
    __builtin_amdgcn_s_setprio(0);
    if(pf) asm volatile("s_waitcnt vmcnt(4)" ::: "memory");
    else   asm volatile("s_waitcnt vmcnt(0)" ::: "memory");
    __builtin_amdgcn_sched_barrier(0);
    __builtin_amdgcn_s_barrier();
    // ---- phase 3: k1, m0..3 ----
    #pragma unroll
    for(int m = 0; m < 4; ++m) af[m] = LDA_(cb, 1, m);
    #pragma unroll
    for(int n = 0; n < 4; ++n) bfr[n] = LDB_(cb, 1, n);
    if(pf) stageHalf(nb, 0, 1, kt + 1);
    __builtin_amdgcn_s_barrier();
    asm volatile("s_waitcnt lgkmcnt(0)" ::: "memory");
    __builtin_amdgcn_sched_barrier(0);
    __builtin_amdgcn_s_setprio(1);
    #pragma unroll
    for(int m = 0; m < 4; ++m)
      #pragma unroll
      for(int n = 0; n < 4; ++n)
        acc[m][n] = __builtin_amdgcn_mfma_f32_16x16x32_bf16(af[m], bfr[n], acc[m][n], 0, 0, 0);
    __builtin_amdgcn_s_setprio(0);
    __builtin_amdgcn_sched_barrier(0);
    __builtin_amdgcn_s_barrier();
    // ---- phase 4: k1, m4..7 ----
    #pragma unroll
    for(int m = 0; m < 4; ++m) af[4 + m] = LDA_(cb, 1, 4 + m);
    if(pf) stageHalf(nb, 1, 1, kt + 1);
    __builtin_amdgcn_s_barrier();
    asm volatile("s_waitcnt lgkmcnt(0)" ::: "memory");
    __builtin_amdgcn_sched_barrier(0);
    __builtin_amdgcn_s_setprio(1);
    #pragma unroll
    for(int m = 0; m < 4; ++m)
      #pragma unroll
      for(int n = 0; n < 4; ++n)
        acc[4 + m][n] = __builtin_amdgcn_mfma_f32_16x16x32_bf16(af[4 + m], bfr[n], acc[4 + m][n], 0, 0, 0);
    __builtin_amdgcn_s_setprio(0);
    if(pf) asm volatile("s_waitcnt vmcnt(4)" ::: "memory");
    __builtin_amdgcn_sched_barrier(0);
    __builtin_amdgcn_s_barrier();
  }

  constexpr float CE = 0.03125f * 1.44269504088896f;  // attn scale * log2(e), folded into q
  #pragma unroll
  for(int m = 0; m < 8; ++m){
    #pragma unroll
    for(int n = 0; n < 4; ++n){
      #pragma unroll
      for(int r = 0; r < 4; ++r){
        const int row = m0 + wm * 128 + m * 16 + lg * 4 + r;
        const int col = n0 + wn * 64 + n * 16 + lq;
        float val = acc[m][n][r];
        if constexpr(MODE == 0){
          int which = col >> 10, hh = (col >> 6) & 15, f = col & 63;
          int b = row >> 11, t = row & 2047;
          if(which == 0) val *= CE;
          u16* dst = (which == 0) ? qo : ((which == 1) ? ko : vo);
          dst[((((long)(b * 16 + hh)) << 11 | t) << 6) | f] = f2bf(val);
        } else {
          const float z = val + bias[col];
          outh[(long)row * N + col] = f2bf(z > 0.f ? z : 0.f);
        }
      }
    }
  }
}

// ======== 256x128 8-wave BK=64 GEMM, 2 phases/tile: C = A*BT^T + bias + resid ======
__global__ __launch_bounds__(512) void k_gemmN128(
    const u16* __restrict__ A, const u16* __restrict__ BT,
    int M, int N, int K,
    const float* __restrict__ bias, const float* __restrict__ resid,
    float* __restrict__ outf){
  __shared__ __align__(16) u16 lds[49152];   // 96 KiB: [2][A 2kh 256x32 | B 2kh 128x32]
  const int tid = threadIdx.x;
  const int wid = tid >> 6, lane = tid & 63;
  const int lq = lane & 15, lg = lane >> 4;
  const int wm = wid >> 1, wn = wid & 1;
  const int rsw = (lq >> 1) & 3;

  const int nwg = gridDim.x;
  const int orig = blockIdx.x;
  const int wg = (orig & 7) * (nwg >> 3) + (orig >> 3);
  const int NT = N >> 7;
  const int gsz = 8 * NT;
  const int gid = wg / gsz, rem = wg % gsz;
  const int m0 = (gid * 8 + (rem & 7)) << 8;
  const int n0 = (rem >> 3) << 7;

  const int NTILES = K >> 6;

  auto stageA = [&](int buf, int kh, int kt){
    const long kcol = (long)kt * 64 + kh * 32;
    u16* dstb = &lds[buf * 24576 + kh * 8192];
    #pragma unroll
    for(int c = 0; c < 2; ++c){
      int g = c * 512 + tid;
      int row = g >> 2, p = g & 3;
      int sp = p ^ ((row >> 1) & 3);
      gload_lds16(A + (long)(m0 + row) * K + kcol + sp * 8, dstb + g * 8);
    }
  };
  auto stageB = [&](int buf, int kh, int kt){
    const long kcol = (long)kt * 64 + kh * 32;
    u16* dstb = &lds[buf * 24576 + 16384 + kh * 4096];
    int row = tid >> 2, p = tid & 3;
    int sp = p ^ ((row >> 1) & 3);
    gload_lds16(BT + (long)(n0 + row) * K + kcol + sp * 8, dstb + tid * 8);
  };
  auto LDA_ = [&](int buf, int kk, int m)->short8{
    return *(const short8*)&lds[buf * 24576 + kk * 8192 +
                                (wm * 64 + m * 16 + lq) * 32 + ((lg ^ rsw) * 8)];
  };
  auto LDB_ = [&](int buf, int kk, int n)->short8{
    return *(const short8*)&lds[buf * 24576 + 16384 + kk * 4096 +
                                (wn * 64 + n * 16 + lq) * 32 + ((lg ^ rsw) * 8)];
  };

  f32x4 acc[4][4] = {};
  short8 af[4], bfr[4];

  stageA(0, 0, 0); stageB(0, 0, 0); stageA(0, 1, 0); stageB(0, 1, 0);
  asm volatile("s_waitcnt vmcnt(3)" ::: "memory");
  __builtin_amdgcn_s_barrier();

  for(int kt = 0; kt < NTILES; ++kt){
    const int cb = kt & 1, nb = cb ^ 1;
    const bool pf = (kt + 1 < NTILES);
    // ---- phase 1: kk0 ----
    #pragma unroll
    for(int m = 0; m < 4; ++m) af[m] = LDA_(cb, 0, m);
    #pragma unroll
    for(int n = 0; n < 4; ++n) bfr[n] = LDB_(cb, 0, n);
    if(pf){ stageA(nb, 0, kt + 1); stageB(nb, 0, kt + 1); }
    __builtin_amdgcn_s_barrier();
    asm volatile("s_waitcnt lgkmcnt(0)" ::: "memory");
    __builtin_amdgcn_sched_barrier(0);
    __builtin_amdgcn_s_setprio(1);
    #pragma unroll
    for(int m = 0; m < 4; ++m)
      #pragma unroll
      for(int n = 0; n < 4; ++n)
        acc[m][n] = __builtin_amdgcn_mfma_f32_16x16x32_bf16(af[m], bfr[n], acc[m][n], 0, 0, 0);
    __builtin_amdgcn_s_setprio(0);
    if(pf) asm volatile("s_waitcnt vmcnt(3)" ::: "memory");
    else   asm volatile("s_waitcnt vmcnt(0)" ::: "memory");
    __builtin_amdgcn_sched_barrier(0);
    __builtin_amdgcn_s_barrier();
    // ---- phase 2: kk1 ----
    #pragma unroll
    for(int m = 0; m < 4; ++m) af[m] = LDA_(cb, 1, m);
    #pragma unroll
    for(int n = 0; n < 4; ++n) bfr[n] = LDB_(cb, 1, n);
    if(pf){ stageA(nb, 1, kt + 1); stageB(nb, 1, kt + 1); }
    __builtin_amdgcn_s_barrier();
    asm volatile("s_waitcnt lgkmcnt(0)" ::: "memory");
    __builtin_amdgcn_sched_barrier(0);
    __builtin_amdgcn_s_setprio(1);
    #pragma unroll
    for(int m = 0; m < 4; ++m)
      #pragma unroll
      for(int n = 0; n < 4; ++n)
        acc[m][n] = __builtin_amdgcn_mfma_f32_16x16x32_bf16(af[m], bfr[n], acc[m][n], 0, 0, 0);
    __builtin_amdgcn_s_setprio(0);
    if(pf){
      asm volatile("s_waitcnt vmcnt(3)" ::: "memory");
      __builtin_amdgcn_sched_barrier(0);
      __builtin_amdgcn_s_barrier();
    }
  }

  #pragma unroll
  for(int m = 0; m < 4; ++m)
    #pragma unroll
    for(int n = 0; n < 4; ++n)
      #pragma unroll
      for(int r = 0; r < 4; ++r){
        const int row = m0 + wm * 64 + m * 16 + lg * 4 + r;
        const int col = n0 + wn * 64 + n * 16 + lq;
        const long o = (long)row * N + col;
        outf[o] = acc[m][n][r] + bias[col] + resid[o];
      }
}

// ---------------- V transpose: [bh][t][f] -> [bh][f][t] ----------------
__global__ __launch_bounds__(256) void k_vtrans(const u16* __restrict__ vb,
                                                u16* __restrict__ vt){
  __shared__ u16 T[64][72];
  const int tid = threadIdx.x;
  const int tt = blockIdx.x, bh = blockIdx.y;
  const long base_in = ((long)bh << 17) + ((long)tt << 12);
  #pragma unroll
  for(int c = 0; c < 2; ++c){
    int idx = (c * 256 + tid) * 8;
    int t = idx >> 6, f = idx & 63;
    short8 v = *(const short8*)(vb + base_in + idx);
    #pragma unroll
    for(int i = 0; i < 8; ++i) T[f + i][t] = (u16)v[i];
  }
  __syncthreads();
  const long base_out = ((long)bh << 17) + tt * 64;
  #pragma unroll
  for(int c = 0; c < 2; ++c){
    int idx = (c * 256 + tid) * 8;
    int f = idx >> 6, t0 = idx & 63;
    short8 o = *(const short8*)&T[f][t0];
    *(short8*)(vt + base_out + (long)f * 2048 + t0) = o;
  }
}

// -------- flash attention v7: causal pair split ACROSS wave groups -----------------
// 512 threads. Waves 0-3 own q-tile qa=i, waves 4-7 own qb=31-i; both share one
// staged K/V stream. Per-wave state = single-tile (fits the 64-VGPR allocation
// the compiler insists on); group A simply skips compute for kv > qa.
__global__ __launch_bounds__(512) void k_attn(const u16* __restrict__ q,
                                              const u16* __restrict__ k,
                                              const u16* __restrict__ vt,
                                              u16* __restrict__ att){
  __shared__ __align__(16) u16 Ks[2][2][64][32];
  __shared__ __align__(16) u16 Vs[2][2][64][32];
  __shared__ __align__(16) u16 Ps[8][16][64];
  const int tid = threadIdx.x, wid = tid >> 6, lane = tid & 63;
  const int lq = lane & 15, lg = lane >> 4;
  const int wloc = wid & 3;
  const int d = blockIdx.x;
  const int bh = (d & 7) * 8 + ((d >> 3) & 7);   // bh-clustered XCD swizzle
  const int i = d >> 6;
  const int qb = 31 - i;
  const int qt = (wid >> 2) ? qb : i;            // this wave's q-tile
  const int b = bh >> 4, h = bh & 15;
  const long bhO = (long)bh << 17;
  const u16* Kg = k + bhO;
  const u16* Vg = vt + bhO;

  short8 qf0, qf1;
  {
    const u16* qrow = q + bhO + ((long)qt << 12) + (wloc * 16 + lq) * 64 + lg * 8;
    qf0 = *(const short8*)(qrow);
    qf1 = *(const short8*)(qrow + 32);
  }

  // 512 threads stage one 16B granule each for K and V (8 KB per matrix per tile)
  auto stageKV = [&](int buf, int kv){
    const int s = tid * 8;
    const int kk = s >> 11, row = (s >> 5) & 63, t = (s >> 3) & 3;
    const int sw = (t ^ ((row >> 1) & 3)) * 8;
    gload_lds16(Kg + (long)kv * 4096 + row * 64 + kk * 32 + sw, &Ks[buf][0][0][0] + s);
    gload_lds16(Vg + (long)row * 2048 + kv * 64 + kk * 32 + sw, &Vs[buf][0][0][0] + s);
  };
  stageKV(0, 0);

  float l_run = 0.f;
  f32x4 Of0 = {}, Of1 = {}, Of2 = {}, Of3 = {};
  const int qg = qt * 64 + wloc * 16 + lq;
  const int swz = (lq >> 1) & 3;
  const int psw = lq & 7;

  for(int kv = 0; kv <= qb; ++kv){
    __syncthreads();
    const int cb = kv & 1;
    if(kv < qb) stageKV(cb ^ 1, kv + 1);
    if(kv <= qt){
      const bool diag = (kv == qt);
      f32x4 sf0 = {}, sf1 = {}, sf2 = {}, sf3 = {};
      #pragma unroll
      for(int kk = 0; kk < 2; ++kk){
        const short8 qf = kk ? qf1 : qf0;
        short8 a0 = *(const short8*)&Ks[cb][kk][ 0 + lq][(lg ^ swz) * 8];
        short8 a1 = *(const short8*)&Ks[cb][kk][16 + lq][(lg ^ swz) * 8];
        short8 a2 = *(const short8*)&Ks[cb][kk][32 + lq][(lg ^ swz) * 8];
        short8 a3 = *(const short8*)&Ks[cb][kk][48 + lq][(lg ^ swz) * 8];
        sf0 = __builtin_amdgcn_mfma_f32_16x16x32_bf16(a0, qf, sf0, 0, 0, 0);
        sf1 = __builtin_amdgcn_mfma_f32_16x16x32_bf16(a1, qf, sf1, 0, 0, 0);
        sf2 = __builtin_amdgcn_mfma_f32_16x16x32_bf16(a2, qf, sf2, 0, 0, 0);
        sf3 = __builtin_amdgcn_mfma_f32_16x16x32_bf16(a3, qf, sf3, 0, 0, 0);
      }
      float se = 0.f;
      #pragma unroll
      for(int r = 0; r < 4; ++r){
        float p0 = __builtin_amdgcn_exp2f(sf0[r]);
        float p1 = __builtin_amdgcn_exp2f(sf1[r]);
        float p2 = __builtin_amdgcn_exp2f(sf2[r]);
        float p3 = __builtin_amdgcn_exp2f(sf3[r]);
        if(diag){
          const int kg = kv * 64 + lg * 4 + r;
          p0 = (kg      > qg) ? 0.f : p0;
          p1 = (kg + 16 > qg) ? 0.f : p1;
          p2 = (kg + 32 > qg) ? 0.f : p2;
          p3 = (kg + 48 > qg) ? 0.f : p3;
        }
        sf0[r] = p0; sf1[r] = p1; sf2[r] = p2; sf3[r] = p3;
        se += (p0 + p1) + (p2 + p3);
      }
      {
        uint2 w0, w1, w2, w3;
        w0.x = cvtpk(sf0[0], sf0[1]); w0.y = cvtpk(sf0[2], sf0[3]);
        w1.x = cvtpk(sf1[0], sf1[1]); w1.y = cvtpk(sf1[2], sf1[3]);
        w2.x = cvtpk(sf2[0], sf2[1]); w2.y = cvtpk(sf2[2], sf2[3]);
        w3.x = cvtpk(sf3[0], sf3[1]); w3.y = cvtpk(sf3[2], sf3[3]);
        *(uint2*)&Ps[wid][lq][((0 + (lg >> 1)) ^ psw) * 8 + (lg & 1) * 4] = w0;
        *(uint2*)&Ps[wid][lq][((2 + (lg >> 1)) ^ psw) * 8 + (lg & 1) * 4] = w1;
        *(uint2*)&Ps[wid][lq][((4 + (lg >> 1)) ^ psw) * 8 + (lg & 1) * 4] = w2;
        *(uint2*)&Ps[wid][lq][((6 + (lg >> 1)) ^ psw) * 8 + (lg & 1) * 4] = w3;
      }
      se += __shfl_xor(se, 16);
      se += __shfl_xor(se, 32);
      l_run += se;
      #pragma unroll
      for(int kk = 0; kk < 2; ++kk){
        short8 ap = *(const short8*)&Ps[wid][lq][((kk * 4 + lg) ^ psw) * 8];
        short8 b0 = *(const short8*)&Vs[cb][kk][ 0 + lq][(lg ^ swz) * 8];
        short8 b1 = *(const short8*)&Vs[cb][kk][16 + lq][(lg ^ swz) * 8];
        short8 b2 = *(const short8*)&Vs[cb][kk][32 + lq][(lg ^ swz) * 8];
        short8 b3 = *(const short8*)&Vs[cb][kk][48 + lq][(lg ^ swz) * 8];
        Of0 = __builtin_amdgcn_mfma_f32_16x16x32_bf16(ap, b0, Of0, 0, 0, 0);
        Of1 = __builtin_amdgcn_mfma_f32_16x16x32_bf16(ap, b1, Of1, 0, 0, 0);
        Of2 = __builtin_amdgcn_mfma_f32_16x16x32_bf16(ap, b2, Of2, 0, 0, 0);
        Of3 = __builtin_amdgcn_mfma_f32_16x16x32_bf16(ap, b3, Of3, 0, 0, 0);
      }
    }
  }

  const float rl = 1.f / l_run;
  #pragma unroll
  for(int r = 0; r < 4; ++r){
    const float il = __shfl(rl, lg * 4 + r);
    const long grow = (long)b * 2048 + qt * 64 + wloc * 16 + lg * 4 + r;
    att[grow * 1024 + h * 64 +  0 + lq] = f2bf(Of0[r] * il);
    att[grow * 1024 + h * 64 + 16 + lq] = f2bf(Of1[r] * il);
    att[grow * 1024 + h * 64 + 32 + lq] = f2bf(Of2[r] * il);
    att[grow * 1024 + h * 64 + 48 + lq] = f2bf(Of3[r] * il);
  }
}

extern "C" void kernel_launch(void* const* d_in, const int* in_sizes, int n_in,
                              void* d_out, int out_size, void* d_ws, size_t ws_size,
                              hipStream_t stream){
  const float* x      = (const float*)d_in[0];
  const float* wq     = (const float*)d_in[1];
  const float* wk     = (const float*)d_in[2];
  const float* wv     = (const float*)d_in[3];
  const float* w_proj = (const float*)d_in[4];
  const float* b_proj = (const float*)d_in[5];
  const float* g1     = (const float*)d_in[6];
  const float* beta1  = (const float*)d_in[7];
  const float* g2     = (const float*)d_in[8];
  const float* beta2  = (const float*)d_in[9];
  const float* w1     = (const float*)d_in[10];
  const float* bf1    = (const float*)d_in[11];
  const float* w2     = (const float*)d_in[12];
  const float* bf2    = (const float*)d_in[13];
  float* out = (float*)d_out;

  u16* WqkvT  = (u16*)d_ws;
  u16* wprojT = WqkvT  + (long)3072 * 1024;
  u16* w1T    = wprojT + (long)1024 * 1024;
  u16* w2T    = w1T    + (long)4096 * 1024;
  u16* h1     = w2T    + (long)4096 * 1024;   // reused for h2
  u16* qb     = h1     + (long)8192 * 1024;
  u16* kb     = qb     + (long)8388608;
  u16* vb     = kb     + (long)8388608;
  u16* tb     = vb     + (long)8388608;       // V^T; att output reuses vb
  u16* a1     = qb;                            // FF1 activation reuses q/k/v/t span
  float* x2   = (float*)(tb + (long)8388608);

  k_ttq<<<dim3(16, 48), 256, 0, stream>>>(wq, wk, wv, WqkvT);
  k_tt<<<dim3(16, 16), 256, 0, stream>>>(w_proj, wprojT, 1024, 1024);
  k_tt<<<dim3(16, 64), 256, 0, stream>>>(w1, w1T, 4096, 1024);
  k_tt<<<dim3(64, 16), 256, 0, stream>>>(w2, w2T, 1024, 4096);

  k_ln<<<8192, 256, 0, stream>>>(x, g1, beta1, h1);
  k_gemm256<0><<<384, 512, 0, stream>>>(h1, WqkvT, 8192, 3072, 1024,
      nullptr, nullptr, qb, kb, vb);
  k_vtrans<<<dim3(32, 64), 256, 0, stream>>>(vb, tb);
  k_attn<<<1024, 512, 0, stream>>>(qb, kb, tb, vb);
  k_gemmN128<<<256, 512, 0, stream>>>(vb, wprojT, 8192, 1024, 1024,
      b_proj, x, x2);
  k_ln<<<8192, 256, 0, stream>>>(x2, g2, beta2, h1);
  k_gemm256<2><<<512, 512, 0, stream>>>(h1, w1T, 8192, 4096, 1024,
      bf1, a1, nullptr, nullptr, nullptr);
  k_gemmN128<<<256, 512, 0, stream>>>(a1, w2T, 8192, 1024, 4096,
      bf2, x2, out);
}